// Round 5
// baseline (527.767 us; speedup 1.0000x reference)
//
#include <hip/hip_runtime.h>

typedef unsigned short u16;
typedef unsigned int u32;

#define LSEQ 4096
#define NPOS 8192

__device__ __forceinline__ float bf2f(u16 u){
  union { u32 i; float f; } v; v.i = ((u32)u) << 16; return v.f;
}
__device__ __forceinline__ u16 f2bf(float f){
  union { float f; u32 i; } v; v.f = f;
  u32 x = v.i;
  return (u16)((x + 0x7fffu + ((x >> 16) & 1u)) >> 16);
}
__device__ __forceinline__ float2 up2(u32 u){
  union { u32 i; float f; } a, b;
  a.i = u << 16; b.i = u & 0xffff0000u;
  float2 r; r.x = a.f; r.y = b.f; return r;
}
__device__ __forceinline__ u32 pk2(float a, float b){
  return (u32)f2bf(a) | ((u32)f2bf(b) << 16);
}
__device__ __forceinline__ float silu_f(float x){ return x / (1.f + __expf(-x)); }
__device__ __forceinline__ float softplus_f(float x){
  return fmaxf(x, 0.f) + log1pf(__expf(-fabsf(x)));
}
// wave broadcast: value of v in lane l (compile-time l) -> SGPR
__device__ __forceinline__ float rdl(float v, int l){
  return __int_as_float(__builtin_amdgcn_readlane(__float_as_int(v), l));
}

// ---- pack weights bf16-pairs + transposes + A = -exp(A_log) ------------
// ipP[c*128+j]   = pk2(ipw[j][c],        ipw[j+128][c])        j in [0,128)
// xpP[dd*64+o]   = pk2(xpw[o][2dd],      xpw[o][2dd+1])
// opP[dd*64+o]   = pk2(opw[o][2dd],      opw[o][2dd+1])
__global__ __launch_bounds__(256) void k_prep(
    const float* __restrict__ ipw, const float* __restrict__ xpw,
    const float* __restrict__ dtw, const float* __restrict__ opw,
    const float* __restrict__ w1, const float* __restrict__ w2,
    const float* __restrict__ w3, const float* __restrict__ alog,
    u32* __restrict__ ipP, u32* __restrict__ xpP, u32* __restrict__ opP,
    float* __restrict__ dtT, float* __restrict__ w1T,
    float* __restrict__ w2T, float* __restrict__ w3T,
    float* __restrict__ Aneg)
{
  int t = blockIdx.x * 256 + threadIdx.x;
  if (t < 8192){
    int c = t >> 7, j = t & 127;
    ipP[t] = pk2(ipw[j*64 + c], ipw[(j + 128)*64 + c]);
  }
  if (t < 4096){
    int dd = t >> 6, o = t & 63;
    xpP[t] = pk2(xpw[o*128 + 2*dd], xpw[o*128 + 2*dd + 1]);
    opP[t] = pk2(opw[o*128 + 2*dd], opw[o*128 + 2*dd + 1]);
    int d = t >> 5, r = t & 31;
    dtT[r*128 + d] = dtw[t];
    int o2 = t >> 6, c2 = t & 63;
    w1T[c2*64 + o2] = w1[t]; w2T[c2*64 + o2] = w2[t]; w3T[c2*64 + o2] = w3[t];
  }
  if (t < 2048){ Aneg[t] = -__expf(alog[t]); }
}

// ---- input 1x1 convs, LDS-tiled: [B,C,L] -> [N,64] position-major ------
__global__ __launch_bounds__(256) void k_convin(
    const float* __restrict__ rgb, const float* __restrict__ dte,
    const float* __restrict__ w1T, const float* __restrict__ b1,
    const float* __restrict__ w2T, const float* __restrict__ b2,
    float* __restrict__ rgbp, float* __restrict__ dtep)
{
  __shared__ __align__(16) float xt[64][64];
  __shared__ __align__(16) float ot[64][65];
  const int tid = threadIdx.x;
  const int which = blockIdx.x & 1;
  const int n0 = (blockIdx.x >> 1) * 64;
  const int b = n0 >> 12, l0 = n0 & 4095;
  const float* src = which ? dte : rgb;
  const float* wT  = which ? w2T : w1T;
  const float* bb  = which ? b2 : b1;
  float* o = which ? dtep : rgbp;

  #pragma unroll
  for (int j = 0; j < 16; j++){
    int idx = tid + 256 * j;
    int c = idx >> 6, p = idx & 63;
    xt[c][p] = src[(size_t)b * 262144 + (size_t)c * 4096 + l0 + p];
  }
  __syncthreads();

  const int pos = tid & 63;
  const int cb  = (tid >> 6) * 16;
  float acc[16];
  #pragma unroll
  for (int j = 0; j < 16; j++) acc[j] = bb[cb + j];
  for (int c = 0; c < 64; c++){
    float xv = xt[c][pos];
    #pragma unroll
    for (int j = 0; j < 16; j++) acc[j] += wT[c*64 + cb + j] * xv;
  }
  #pragma unroll
  for (int j = 0; j < 16; j++) ot[pos][cb + j] = acc[j];
  __syncthreads();
  #pragma unroll
  for (int j = 0; j < 16; j++){
    int idx = tid + 256 * j;
    int p = idx >> 6, c = idx & 63;
    o[(size_t)(n0 + p)*64 + c] = ot[p][c];
  }
}

// ---- block-0 pre: rmsnorm + in_proj (LDS weights + readlane) -----------
__global__ __launch_bounds__(512) void k_pre(
    const float* __restrict__ xin, const float* __restrict__ normw,
    const u32* __restrict__ wpk,
    float* __restrict__ xn, float* __restrict__ xcp, float* __restrict__ zs)
{
  __shared__ u32 ipS[8192];
  const int tid = threadIdx.x;
  #pragma unroll
  for (int j = 0; j < 4; j++)
    ((uint4*)ipS)[tid + 512*j] = ((const uint4*)wpk)[tid + 512*j];
  __syncthreads();

  const int wv = tid >> 6, lane = tid & 63;
  const int n0 = (blockIdx.x * 8 + wv) * 2;
  float nw = normw[lane];
  float v[2];
  #pragma unroll
  for (int p = 0; p < 2; p++){
    int n = n0 + p;
    float x = xin[(size_t)n*64 + lane];
    float ss = x * x;
    for (int m = 32; m > 0; m >>= 1) ss += __shfl_xor(ss, m);
    x = x * rsqrtf(ss * (1.f/64.f) + 1e-5f) * nw;
    v[p] = x;
    xn[(size_t)n*64 + lane] = x;
  }
  float ax0[2] = {0,0}, ax1[2] = {0,0}, az0[2] = {0,0}, az1[2] = {0,0};
  #pragma unroll
  for (int c = 0; c < 64; c++){
    float2 wa = up2(ipS[c*128 + lane]);
    float2 wb = up2(ipS[c*128 + 64 + lane]);
    #pragma unroll
    for (int p = 0; p < 2; p++){
      float xv = rdl(v[p], c);
      ax0[p] += wa.x * xv; az0[p] += wa.y * xv;
      ax1[p] += wb.x * xv; az1[p] += wb.y * xv;
    }
  }
  #pragma unroll
  for (int p = 0; p < 2; p++){
    int n = n0 + p;
    xcp[(size_t)n*128 + lane]      = ax0[p];
    xcp[(size_t)n*128 + 64 + lane] = ax1[p];
    zs[(size_t)n*128 + lane]       = silu_f(az0[p]);
    zs[(size_t)n*128 + 64 + lane]  = silu_f(az1[p]);
  }
}

// ---- one Mamba block (+ fused next-block rmsnorm/in_proj) --------------
// 512 thr (8 waves), 2 pos/wave. Weights bf16-packed in LDS (64 KB).
// All cross-lane broadcasts via v_readlane; no working LDS.
__global__ __launch_bounds__(512, 4) void k_step(
    const float* __restrict__ xcpA, float* __restrict__ xcpB,
    float* __restrict__ zs, float* __restrict__ xn,
    u16* __restrict__ hbf, float* __restrict__ hfin,
    const float* __restrict__ base_next, const u32* __restrict__ wpk,
    const float* __restrict__ dtT, const float* __restrict__ Aneg,
    const float* __restrict__ c1w, const float* __restrict__ c1b,
    const float* __restrict__ dtb, const float* __restrict__ Dpw,
    const float* __restrict__ normw, int hasH, int fusePre)
{
  __shared__ u32 wS[16384];     // ipP[8192] | xpP[4096] | opP[4096]
  const int tid = threadIdx.x;
  #pragma unroll
  for (int j = 0; j < 8; j++)
    ((uint4*)wS)[tid + 512*j] = ((const uint4*)wpk)[tid + 512*j];
  const u32* ipS = wS;
  const u32* xpS = wS + 8192;
  const u32* opS = wS + 12288;
  __syncthreads();

  const int wv = tid >> 6, lane = tid & 63;
  const int n0 = (blockIdx.x * 8 + wv) * 2;
  const int d0 = lane, d1 = 64 + lane;

  // prefetch h (packed bf16) early to overlap with compute
  uint4 hr0[2][2], hr1[2][2];
  if (hasH){
    #pragma unroll
    for (int p = 0; p < 2; p++){
      const uint4* q0 = (const uint4*)(hbf + ((size_t)(n0+p)*2048 + (size_t)d0*16));
      const uint4* q1 = (const uint4*)(hbf + ((size_t)(n0+p)*2048 + (size_t)d1*16));
      hr0[p][0] = q0[0]; hr0[p][1] = q0[1];
      hr1[p][0] = q1[0]; hr1[p][1] = q1[1];
    }
  }

  const float cw00 = c1w[d0*3+0], cw01 = c1w[d0*3+1], cw02 = c1w[d0*3+2];
  const float cw10 = c1w[d1*3+0], cw11 = c1w[d1*3+1], cw12 = c1w[d1*3+2];
  const float cb0 = c1b[d0], cb1 = c1b[d1];

  // depthwise conv (radius 1 within batch) + silu
  float xc0[2], xc1[2];
  #pragma unroll
  for (int p = 0; p < 2; p++){
    int n = n0 + p, l = n & 4095;
    const float* xr = xcpA + (size_t)n * 128;
    float am0 = 0.f, am1 = 0.f, ap0 = 0.f, ap1 = 0.f;
    if (l > 0)    { am0 = xr[d0 - 128]; am1 = xr[d1 - 128]; }
    float a00 = xr[d0], a01 = xr[d1];
    if (l < 4095) { ap0 = xr[d0 + 128]; ap1 = xr[d1 + 128]; }
    xc0[p] = silu_f(cw00*am0 + cw01*a00 + cw02*ap0 + cb0);
    xc1[p] = silu_f(cw10*am1 + cw11*a01 + cw12*ap1 + cb1);
  }

  // x_proj: xa[p] = dbc[o=lane]
  float xa[2] = {0.f, 0.f};
  #pragma unroll
  for (int dd = 0; dd < 32; dd++){
    float2 w = up2(xpS[dd*64 + lane]);
    #pragma unroll
    for (int p = 0; p < 2; p++)
      xa[p] += w.x * rdl(xc0[p], 2*dd) + w.y * rdl(xc0[p], 2*dd + 1);
  }
  #pragma unroll
  for (int dd = 32; dd < 64; dd++){
    float2 w = up2(xpS[dd*64 + lane]);
    #pragma unroll
    for (int p = 0; p < 2; p++)
      xa[p] += w.x * rdl(xc1[p], 2*dd - 64) + w.y * rdl(xc1[p], 2*dd - 63);
  }

  // dt_proj + softplus
  float dl0[2], dl1[2];
  {
    float tb0 = dtb[d0], tb1 = dtb[d1];
    float da0[2] = {tb0, tb0}, da1[2] = {tb1, tb1};
    #pragma unroll
    for (int r = 0; r < 32; r++){
      float w0 = dtT[r*128 + d0], w1 = dtT[r*128 + d1];
      #pragma unroll
      for (int p = 0; p < 2; p++){
        float bv = rdl(xa[p], r);
        da0[p] += w0 * bv; da1[p] += w1 * bv;
      }
    }
    #pragma unroll
    for (int p = 0; p < 2; p++){
      dl0[p] = softplus_f(da0[p]); dl1[p] = softplus_f(da1[p]);
    }
  }

  float an0[16], an1[16];
  {
    const float4* A0 = (const float4*)(Aneg + d0*16);
    const float4* A1 = (const float4*)(Aneg + d1*16);
    #pragma unroll
    for (int q = 0; q < 4; q++){
      float4 a = A0[q]; an0[q*4+0]=a.x; an0[q*4+1]=a.y; an0[q*4+2]=a.z; an0[q*4+3]=a.w;
      float4 b = A1[q]; an1[q*4+0]=b.x; an1[q*4+1]=b.y; an1[q*4+2]=b.z; an1[q*4+3]=b.w;
    }
  }
  const float dp0 = Dpw[d0], dp1 = Dpw[d1];

  // SSM update + y; h bf16 intermediate / fp32 final
  float yz0[2], yz1[2];
  #pragma unroll
  for (int p = 0; p < 2; p++){
    int n = n0 + p;
    float h0[16], h1[16];
    if (hasH){
      #pragma unroll
      for (int q = 0; q < 2; q++){
        float2 t0 = up2(hr0[p][q].x), t1 = up2(hr0[p][q].y);
        float2 t2 = up2(hr0[p][q].z), t3 = up2(hr0[p][q].w);
        h0[q*8+0]=t0.x; h0[q*8+1]=t0.y; h0[q*8+2]=t1.x; h0[q*8+3]=t1.y;
        h0[q*8+4]=t2.x; h0[q*8+5]=t2.y; h0[q*8+6]=t3.x; h0[q*8+7]=t3.y;
        float2 s0 = up2(hr1[p][q].x), s1 = up2(hr1[p][q].y);
        float2 s2 = up2(hr1[p][q].z), s3 = up2(hr1[p][q].w);
        h1[q*8+0]=s0.x; h1[q*8+1]=s0.y; h1[q*8+2]=s1.x; h1[q*8+3]=s1.y;
        h1[q*8+4]=s2.x; h1[q*8+5]=s2.y; h1[q*8+6]=s3.x; h1[q*8+7]=s3.y;
      }
    } else {
      #pragma unroll
      for (int s = 0; s < 16; s++){ h0[s] = 0.f; h1[s] = 0.f; }
    }
    float y0 = 0.f, y1 = 0.f;
    float bx0 = dl0[p] * xc0[p], bx1 = dl1[p] * xc1[p];
    #pragma unroll
    for (int s = 0; s < 16; s++){
      float Bs = rdl(xa[p], 32 + s);
      float Cs = rdl(xa[p], 48 + s);
      h0[s] = __expf(dl0[p]*an0[s])*h0[s] + bx0*Bs;
      y0 = fmaf(h0[s], Cs, y0);
      h1[s] = __expf(dl1[p]*an1[s])*h1[s] + bx1*Bs;
      y1 = fmaf(h1[s], Cs, y1);
    }
    if (fusePre){
      u16* o0 = hbf + ((size_t)n*2048 + (size_t)d0*16);
      u16* o1 = hbf + ((size_t)n*2048 + (size_t)d1*16);
      #pragma unroll
      for (int q = 0; q < 2; q++){
        uint4 v;
        v.x = pk2(h0[q*8+0], h0[q*8+1]); v.y = pk2(h0[q*8+2], h0[q*8+3]);
        v.z = pk2(h0[q*8+4], h0[q*8+5]); v.w = pk2(h0[q*8+6], h0[q*8+7]);
        ((uint4*)o0)[q] = v;
        uint4 w;
        w.x = pk2(h1[q*8+0], h1[q*8+1]); w.y = pk2(h1[q*8+2], h1[q*8+3]);
        w.z = pk2(h1[q*8+4], h1[q*8+5]); w.w = pk2(h1[q*8+6], h1[q*8+7]);
        ((uint4*)o1)[q] = w;
      }
    } else {
      float4* f0 = (float4*)(hfin + (size_t)n*2048 + (size_t)d0*16);
      float4* f1 = (float4*)(hfin + (size_t)n*2048 + (size_t)d1*16);
      #pragma unroll
      for (int q = 0; q < 4; q++){
        float4 v; v.x=h0[q*4+0]; v.y=h0[q*4+1]; v.z=h0[q*4+2]; v.w=h0[q*4+3];
        f0[q] = v;
        float4 w; w.x=h1[q*4+0]; w.y=h1[q*4+1]; w.z=h1[q*4+2]; w.w=h1[q*4+3];
        f1[q] = w;
      }
    }
    yz0[p] = (y0 + dp0 * xc0[p]) * zs[(size_t)n*128 + lane];
    yz1[p] = (y1 + dp1 * xc1[p]) * zs[(size_t)n*128 + 64 + lane];
  }

  // out_proj: oa[p] for output channel o=lane
  float oa[2] = {0.f, 0.f};
  #pragma unroll
  for (int dd = 0; dd < 32; dd++){
    float2 w = up2(opS[dd*64 + lane]);
    #pragma unroll
    for (int p = 0; p < 2; p++)
      oa[p] += w.x * rdl(yz0[p], 2*dd) + w.y * rdl(yz0[p], 2*dd + 1);
  }
  #pragma unroll
  for (int dd = 32; dd < 64; dd++){
    float2 w = up2(opS[dd*64 + lane]);
    #pragma unroll
    for (int p = 0; p < 2; p++)
      oa[p] += w.x * rdl(yz1[p], 2*dd - 64) + w.y * rdl(yz1[p], 2*dd - 63);
  }

  const float nw = normw[lane];
  if (fusePre){
    float v[2];
    #pragma unroll
    for (int p = 0; p < 2; p++){
      int n = n0 + p;
      float x = oa[p] + xn[(size_t)n*64 + lane] + base_next[(size_t)n*64 + lane];
      float ss = x * x;
      for (int m = 32; m > 0; m >>= 1) ss += __shfl_xor(ss, m);
      x = x * rsqrtf(ss * (1.f/64.f) + 1e-5f) * nw;
      v[p] = x;
      xn[(size_t)n*64 + lane] = x;
    }
    float ax0[2] = {0,0}, ax1[2] = {0,0}, az0[2] = {0,0}, az1[2] = {0,0};
    #pragma unroll
    for (int c = 0; c < 64; c++){
      float2 wa = up2(ipS[c*128 + lane]);
      float2 wb = up2(ipS[c*128 + 64 + lane]);
      #pragma unroll
      for (int p = 0; p < 2; p++){
        float xv = rdl(v[p], c);
        ax0[p] += wa.x * xv; az0[p] += wa.y * xv;
        ax1[p] += wb.x * xv; az1[p] += wb.y * xv;
      }
    }
    #pragma unroll
    for (int p = 0; p < 2; p++){
      int n = n0 + p;
      xcpB[(size_t)n*128 + lane]      = ax0[p];
      xcpB[(size_t)n*128 + 64 + lane] = ax1[p];
      zs[(size_t)n*128 + lane]        = silu_f(az0[p]);
      zs[(size_t)n*128 + 64 + lane]   = silu_f(az1[p]);
    }
  } else {
    #pragma unroll
    for (int p = 0; p < 2; p++){
      int n = n0 + p;
      xcpB[(size_t)n*64 + lane] = oa[p] + xn[(size_t)n*64 + lane];
    }
  }
}

// ---- final conv1x1, transpose [N,64] -> [B,64,L] -----------------------
__global__ __launch_bounds__(256) void k_conv3(
    const float* __restrict__ out6, const float* __restrict__ w3T,
    const float* __restrict__ b3, float* __restrict__ out)
{
  __shared__ __align__(16) float t[64][65];
  const int tid = threadIdx.x;
  const int n0 = blockIdx.x * 64;
  #pragma unroll
  for (int i = 0; i < 16; i++){
    int idx = tid + 256*i;
    int r = idx >> 6, c = idx & 63;
    t[r][c] = out6[(size_t)(n0 + r)*64 + c];
  }
  __syncthreads();
  const int i = tid & 63;
  const int cb = (tid >> 6) * 16;
  float acc[16];
  #pragma unroll
  for (int j = 0; j < 16; j++) acc[j] = b3[cb + j];
  for (int o = 0; o < 64; o++){
    float xv = t[i][o];
    #pragma unroll
    for (int j = 0; j < 16; j++) acc[j] += w3T[o*64 + cb + j] * xv;
  }
  const int b = n0 >> 12;
  const int l = (n0 & 4095) + i;
  #pragma unroll
  for (int j = 0; j < 16; j++)
    out[(size_t)b*262144 + (size_t)(cb + j)*4096 + l] = acc[j];
}

extern "C" void kernel_launch(void* const* d_in, const int* in_sizes, int n_in,
                              void* d_out, int out_size, void* d_ws, size_t ws_size,
                              hipStream_t stream)
{
  const float* rgb  = (const float*)d_in[0];
  const float* dte  = (const float*)d_in[1];
  const float* w1   = (const float*)d_in[2];
  const float* b1   = (const float*)d_in[3];
  const float* w2   = (const float*)d_in[4];
  const float* b2   = (const float*)d_in[5];
  const float* w3   = (const float*)d_in[6];
  const float* b3   = (const float*)d_in[7];
  const float* nrm  = (const float*)d_in[8];
  const float* ipw  = (const float*)d_in[9];
  const float* c1w  = (const float*)d_in[10];
  const float* c1b  = (const float*)d_in[11];
  const float* xpw  = (const float*)d_in[12];
  const float* dtw  = (const float*)d_in[13];
  const float* dtb  = (const float*)d_in[14];
  const float* alog = (const float*)d_in[15];
  const float* Dpw  = (const float*)d_in[16];
  const float* opw  = (const float*)d_in[17];

  float* outc = (float*)d_out;
  float* hfin = outc + 524288;          // final fp32 h lives in d_out

  float* ws   = (float*)d_ws;
  float* xcp0 = ws;                     // [N,128] ping
  float* xcp1 = ws + 1048576;           // [N,128] pong
  float* rgbp = ws + 2097152;           // [N,64]
  float* dtep = ws + 2621440;           // [N,64]
  float* xnb  = ws + 3145728;           // [N,64]
  float* zsb  = ws + 3670016;           // [N,128]
  u32*   wpk  = (u32*)(ws + 4718592);   // ipP[8192] xpP[4096] opP[4096]
  float* dtT  = ws + 4734976;           // [32][128]
  float* w1T  = ws + 4739072;           // [64][64]
  float* w2T  = ws + 4743168;
  float* w3T  = ws + 4747264;
  float* Aneg = ws + 4751360;           // [128][16]
  u16*   hbf  = (u16*)(ws + 4753408);   // [N,128,16] bf16 intermediate h

  k_prep<<<64, 256, 0, stream>>>(ipw, xpw, dtw, opw, w1, w2, w3, alog,
                                 wpk, wpk + 8192, wpk + 12288,
                                 dtT, w1T, w2T, w3T, Aneg);
  k_convin<<<256, 256, 0, stream>>>(rgb, dte, w1T, b1, w2T, b2, rgbp, dtep);
  k_pre<<<512, 512, 0, stream>>>(rgbp, nrm, wpk, xnb, xcp0, zsb);

  float* xa[2] = {xcp0, xcp1};
  for (int k = 0; k < 6; k++){
    const float* base = (k & 1) ? rgbp : dtep;   // unused when k==5
    k_step<<<512, 512, 0, stream>>>(xa[k & 1], xa[(k & 1) ^ 1], zsb, xnb,
                                    hbf, hfin, base, wpk,
                                    dtT, Aneg, c1w, c1b, dtb, Dpw, nrm,
                                    (k > 0) ? 1 : 0, (k < 5) ? 1 : 0);
  }
  k_conv3<<<128, 256, 0, stream>>>(xcp0, w3T, b3, outc);
}

// Round 6
// 365.279 us; speedup vs baseline: 1.4448x; 1.4448x over previous
//
#include <hip/hip_runtime.h>

typedef unsigned short u16;
typedef unsigned int u32;

#define LSEQ 4096
#define NPOS 8192

__device__ __forceinline__ float bf2f(u16 u){
  union { u32 i; float f; } v; v.i = ((u32)u) << 16; return v.f;
}
__device__ __forceinline__ u16 f2bf(float f){
  union { float f; u32 i; } v; v.f = f;
  u32 x = v.i;
  return (u16)((x + 0x7fffu + ((x >> 16) & 1u)) >> 16);
}
__device__ __forceinline__ float2 up2(u32 u){
  union { u32 i; float f; } a, b;
  a.i = u << 16; b.i = u & 0xffff0000u;
  float2 r; r.x = a.f; r.y = b.f; return r;
}
__device__ __forceinline__ u32 pk2(float a, float b){
  return (u32)f2bf(a) | ((u32)f2bf(b) << 16);
}
__device__ __forceinline__ void up8(uint4 v, float* f){
  float2 a = up2(v.x); f[0]=a.x; f[1]=a.y;
  float2 b = up2(v.y); f[2]=b.x; f[3]=b.y;
  float2 c = up2(v.z); f[4]=c.x; f[5]=c.y;
  float2 d = up2(v.w); f[6]=d.x; f[7]=d.y;
}
__device__ __forceinline__ float silu_f(float x){ return x / (1.f + __expf(-x)); }
__device__ __forceinline__ float softplus_f(float x){
  return fmaxf(x, 0.f) + log1pf(__expf(-fabsf(x)));
}
// wave broadcast: value of v in lane l (compile-time l)
__device__ __forceinline__ float rdl(float v, int l){
  return __int_as_float(__builtin_amdgcn_readlane(__float_as_int(v), l));
}

// ---- pack weights into per-lane-contiguous bf16 dwordx4 tiles ----------
// xpI[q*64+o]        = xpw[o][q*8 .. q*8+7]        (q<16, o<64)
// opI[q*64+o]        = opw[o][q*8 .. q*8+7]
// dtI[q*128+d]       = dtw[d][q*8 .. q*8+7]        (q<4, d<128)
// ipI[(jj*8+q)*64+o] = ipw[jj*64+o][q*8 .. q*8+7]  (jj<4, q<8, o<64)
__global__ __launch_bounds__(256) void k_prep(
    const float* __restrict__ ipw, const float* __restrict__ xpw,
    const float* __restrict__ dtw, const float* __restrict__ opw,
    const float* __restrict__ w1, const float* __restrict__ w2,
    const float* __restrict__ w3, const float* __restrict__ alog,
    uint4* __restrict__ xpI, uint4* __restrict__ opI,
    uint4* __restrict__ dtI, uint4* __restrict__ ipI,
    float* __restrict__ Aneg, float* __restrict__ w1T,
    float* __restrict__ w2T, float* __restrict__ w3T)
{
  int t = blockIdx.x * 256 + threadIdx.x;
  if (t < 1024){
    int q = t >> 6, o = t & 63;
    const float* s = xpw + o*128 + q*8;
    uint4 v; v.x = pk2(s[0],s[1]); v.y = pk2(s[2],s[3]);
    v.z = pk2(s[4],s[5]); v.w = pk2(s[6],s[7]);
    xpI[t] = v;
    const float* u = opw + o*128 + q*8;
    uint4 w; w.x = pk2(u[0],u[1]); w.y = pk2(u[2],u[3]);
    w.z = pk2(u[4],u[5]); w.w = pk2(u[6],u[7]);
    opI[t] = w;
  }
  if (t < 512){
    int q = t >> 7, d = t & 127;
    const float* s = dtw + d*32 + q*8;
    uint4 v; v.x = pk2(s[0],s[1]); v.y = pk2(s[2],s[3]);
    v.z = pk2(s[4],s[5]); v.w = pk2(s[6],s[7]);
    dtI[t] = v;
  }
  if (t < 2048){
    int o = t & 63, qq = t >> 6;          // qq in [0,32)
    int jj = qq >> 3, q = qq & 7;
    const float* s = ipw + (jj*64 + o)*64 + q*8;
    uint4 v; v.x = pk2(s[0],s[1]); v.y = pk2(s[2],s[3]);
    v.z = pk2(s[4],s[5]); v.w = pk2(s[6],s[7]);
    ipI[t] = v;
    Aneg[t] = -__expf(alog[t]);
  }
  if (t < 4096){
    int o = t >> 6, c = t & 63;
    w1T[c*64+o] = w1[t]; w2T[c*64+o] = w2[t]; w3T[c*64+o] = w3[t];
  }
}

// ---- input 1x1 convs, LDS-tiled: [B,C,L] -> [N,64] position-major ------
__global__ __launch_bounds__(256) void k_convin(
    const float* __restrict__ rgb, const float* __restrict__ dte,
    const float* __restrict__ w1T, const float* __restrict__ b1,
    const float* __restrict__ w2T, const float* __restrict__ b2,
    float* __restrict__ rgbp, float* __restrict__ dtep)
{
  __shared__ __align__(16) float xt[64][64];
  __shared__ __align__(16) float ot[64][65];
  const int tid = threadIdx.x;
  const int which = blockIdx.x & 1;
  const int n0 = (blockIdx.x >> 1) * 64;
  const int b = n0 >> 12, l0 = n0 & 4095;
  const float* src = which ? dte : rgb;
  const float* wT  = which ? w2T : w1T;
  const float* bb  = which ? b2 : b1;
  float* o = which ? dtep : rgbp;

  #pragma unroll
  for (int j = 0; j < 16; j++){
    int idx = tid + 256 * j;
    int c = idx >> 6, p = idx & 63;
    xt[c][p] = src[(size_t)b * 262144 + (size_t)c * 4096 + l0 + p];
  }
  __syncthreads();

  const int pos = tid & 63;
  const int cb  = (tid >> 6) * 16;
  float acc[16];
  #pragma unroll
  for (int j = 0; j < 16; j++) acc[j] = bb[cb + j];
  for (int c = 0; c < 64; c++){
    float xv = xt[c][pos];
    #pragma unroll
    for (int j = 0; j < 16; j++) acc[j] += wT[c*64 + cb + j] * xv;
  }
  #pragma unroll
  for (int j = 0; j < 16; j++) ot[pos][cb + j] = acc[j];
  __syncthreads();
  #pragma unroll
  for (int j = 0; j < 16; j++){
    int idx = tid + 256 * j;
    int p = idx >> 6, c = idx & 63;
    o[(size_t)(n0 + p)*64 + c] = ot[p][c];
  }
}

// ---- block-0 pre: rmsnorm + in_proj (packed weights + readlane) --------
__global__ __launch_bounds__(256) void k_pre(
    const float* __restrict__ xin, const float* __restrict__ normw,
    const uint4* __restrict__ ipI,
    float* __restrict__ xn, float* __restrict__ xcp, float* __restrict__ zs)
{
  const int wv = threadIdx.x >> 6, lane = threadIdx.x & 63;
  const int n0 = (blockIdx.x * 4 + wv) * 2;
  float nw = normw[lane];
  float v[2];
  #pragma unroll
  for (int p = 0; p < 2; p++){
    int n = n0 + p;
    float x = xin[(size_t)n*64 + lane];
    float ss = x * x;
    for (int m = 32; m > 0; m >>= 1) ss += __shfl_xor(ss, m);
    x = x * rsqrtf(ss * (1.f/64.f) + 1e-5f) * nw;
    v[p] = x;
    xn[(size_t)n*64 + lane] = x;
  }
  float ac[4][2] = {};
  #pragma unroll
  for (int q = 0; q < 8; q++){
    uint4 w4[4];
    #pragma unroll
    for (int jj = 0; jj < 4; jj++) w4[jj] = ipI[(jj*8+q)*64 + lane];
    float wf[4][8];
    #pragma unroll
    for (int jj = 0; jj < 4; jj++) up8(w4[jj], wf[jj]);
    #pragma unroll
    for (int j = 0; j < 8; j++){
      int c = q*8 + j;
      float b0 = rdl(v[0], c), b1 = rdl(v[1], c);
      #pragma unroll
      for (int jj = 0; jj < 4; jj++){
        ac[jj][0] = fmaf(wf[jj][j], b0, ac[jj][0]);
        ac[jj][1] = fmaf(wf[jj][j], b1, ac[jj][1]);
      }
    }
  }
  #pragma unroll
  for (int p = 0; p < 2; p++){
    int n = n0 + p;
    xcp[(size_t)n*128 + lane]      = ac[0][p];
    xcp[(size_t)n*128 + 64 + lane] = ac[1][p];
    zs[(size_t)n*128 + lane]       = silu_f(ac[2][p]);
    zs[(size_t)n*128 + 64 + lane]  = silu_f(ac[3][p]);
  }
}

// ---- one Mamba block (+ fused next-block rmsnorm/in_proj) --------------
// 256 thr (4 waves), 2 pos/wave. Weights: packed bf16 dwordx4 global loads
// (one latency window per phase). Broadcasts: v_readlane. No working LDS.
__global__ __launch_bounds__(256) void k_step(
    const float* __restrict__ xcpA, float* __restrict__ xcpB,
    float* __restrict__ zs, float* __restrict__ xn,
    u16* __restrict__ hbf, float* __restrict__ hfin,
    const float* __restrict__ base_next,
    const uint4* __restrict__ xpI, const uint4* __restrict__ opI,
    const uint4* __restrict__ dtI, const uint4* __restrict__ ipI,
    const float* __restrict__ Aneg, const float* __restrict__ c1w,
    const float* __restrict__ c1b, const float* __restrict__ dtb,
    const float* __restrict__ Dpw, const float* __restrict__ normw,
    int hasH, int fusePre)
{
  const int wv = threadIdx.x >> 6, lane = threadIdx.x & 63;
  const int n0 = (blockIdx.x * 4 + wv) * 2;
  const int d0 = lane, d1 = 64 + lane;

  // prefetch h (packed bf16)
  uint4 hr0[2][2], hr1[2][2];
  if (hasH){
    #pragma unroll
    for (int p = 0; p < 2; p++){
      const uint4* q0 = (const uint4*)(hbf + ((size_t)(n0+p)*2048 + (size_t)d0*16));
      const uint4* q1 = (const uint4*)(hbf + ((size_t)(n0+p)*2048 + (size_t)d1*16));
      hr0[p][0] = q0[0]; hr0[p][1] = q0[1];
      hr1[p][0] = q1[0]; hr1[p][1] = q1[1];
    }
  }

  const float cw00 = c1w[d0*3+0], cw01 = c1w[d0*3+1], cw02 = c1w[d0*3+2];
  const float cw10 = c1w[d1*3+0], cw11 = c1w[d1*3+1], cw12 = c1w[d1*3+2];
  const float cb0 = c1b[d0], cb1 = c1b[d1];

  // depthwise conv (radius 1 within batch) + silu
  float xc0[2], xc1[2];
  #pragma unroll
  for (int p = 0; p < 2; p++){
    int n = n0 + p, l = n & 4095;
    const float* xr = xcpA + (size_t)n * 128;
    float am0 = 0.f, am1 = 0.f, ap0 = 0.f, ap1 = 0.f;
    if (l > 0)    { am0 = xr[d0 - 128]; am1 = xr[d1 - 128]; }
    float a00 = xr[d0], a01 = xr[d1];
    if (l < 4095) { ap0 = xr[d0 + 128]; ap1 = xr[d1 + 128]; }
    xc0[p] = silu_f(cw00*am0 + cw01*a00 + cw02*ap0 + cb0);
    xc1[p] = silu_f(cw10*am1 + cw11*a01 + cw12*ap1 + cb1);
  }

  // x_proj: xa[p] = dbc[o=lane]; 16 coalesced dwordx4 weight loads
  float xa[2] = {0.f, 0.f};
  #pragma unroll
  for (int q = 0; q < 16; q++){
    uint4 w4 = xpI[q*64 + lane];
    float wf[8]; up8(w4, wf);
    #pragma unroll
    for (int j = 0; j < 8; j++){
      int d = q*8 + j;
      float b0, b1;
      if (d < 64){ b0 = rdl(xc0[0], d);      b1 = rdl(xc0[1], d); }
      else       { b0 = rdl(xc1[0], d - 64); b1 = rdl(xc1[1], d - 64); }
      xa[0] = fmaf(wf[j], b0, xa[0]);
      xa[1] = fmaf(wf[j], b1, xa[1]);
    }
  }

  // dt_proj + softplus; 8 coalesced dwordx4 loads
  float dl0[2], dl1[2];
  {
    float tb0 = dtb[d0], tb1 = dtb[d1];
    float da0[2] = {tb0, tb0}, da1[2] = {tb1, tb1};
    #pragma unroll
    for (int q = 0; q < 4; q++){
      uint4 w40 = dtI[q*128 + d0];
      uint4 w41 = dtI[q*128 + d1];
      float f0[8], f1[8]; up8(w40, f0); up8(w41, f1);
      #pragma unroll
      for (int j = 0; j < 8; j++){
        int r = q*8 + j;
        float bv0 = rdl(xa[0], r), bv1 = rdl(xa[1], r);
        da0[0] = fmaf(f0[j], bv0, da0[0]); da0[1] = fmaf(f0[j], bv1, da0[1]);
        da1[0] = fmaf(f1[j], bv0, da1[0]); da1[1] = fmaf(f1[j], bv1, da1[1]);
      }
    }
    dl0[0] = softplus_f(da0[0]); dl0[1] = softplus_f(da0[1]);
    dl1[0] = softplus_f(da1[0]); dl1[1] = softplus_f(da1[1]);
  }

  float an0[16], an1[16];
  {
    const float4* A0 = (const float4*)(Aneg + d0*16);
    const float4* A1 = (const float4*)(Aneg + d1*16);
    #pragma unroll
    for (int q = 0; q < 4; q++){
      float4 a = A0[q]; an0[q*4+0]=a.x; an0[q*4+1]=a.y; an0[q*4+2]=a.z; an0[q*4+3]=a.w;
      float4 b = A1[q]; an1[q*4+0]=b.x; an1[q*4+1]=b.y; an1[q*4+2]=b.z; an1[q*4+3]=b.w;
    }
  }
  const float dp0 = Dpw[d0], dp1 = Dpw[d1];

  // SSM update + y
  float yz0[2], yz1[2];
  #pragma unroll
  for (int p = 0; p < 2; p++){
    int n = n0 + p;
    float h0[16], h1[16];
    if (hasH){
      #pragma unroll
      for (int q = 0; q < 2; q++){
        float2 t0 = up2(hr0[p][q].x), t1 = up2(hr0[p][q].y);
        float2 t2 = up2(hr0[p][q].z), t3 = up2(hr0[p][q].w);
        h0[q*8+0]=t0.x; h0[q*8+1]=t0.y; h0[q*8+2]=t1.x; h0[q*8+3]=t1.y;
        h0[q*8+4]=t2.x; h0[q*8+5]=t2.y; h0[q*8+6]=t3.x; h0[q*8+7]=t3.y;
        float2 s0 = up2(hr1[p][q].x), s1 = up2(hr1[p][q].y);
        float2 s2 = up2(hr1[p][q].z), s3 = up2(hr1[p][q].w);
        h1[q*8+0]=s0.x; h1[q*8+1]=s0.y; h1[q*8+2]=s1.x; h1[q*8+3]=s1.y;
        h1[q*8+4]=s2.x; h1[q*8+5]=s2.y; h1[q*8+6]=s3.x; h1[q*8+7]=s3.y;
      }
    } else {
      #pragma unroll
      for (int s = 0; s < 16; s++){ h0[s] = 0.f; h1[s] = 0.f; }
    }
    float y0 = 0.f, y1 = 0.f;
    float bx0 = dl0[p] * xc0[p], bx1 = dl1[p] * xc1[p];
    #pragma unroll
    for (int s = 0; s < 16; s++){
      float Bs = rdl(xa[p], 32 + s);
      float Cs = rdl(xa[p], 48 + s);
      h0[s] = __expf(dl0[p]*an0[s])*h0[s] + bx0*Bs;
      y0 = fmaf(h0[s], Cs, y0);
      h1[s] = __expf(dl1[p]*an1[s])*h1[s] + bx1*Bs;
      y1 = fmaf(h1[s], Cs, y1);
    }
    if (fusePre){
      u16* o0 = hbf + ((size_t)n*2048 + (size_t)d0*16);
      u16* o1 = hbf + ((size_t)n*2048 + (size_t)d1*16);
      #pragma unroll
      for (int q = 0; q < 2; q++){
        uint4 v;
        v.x = pk2(h0[q*8+0], h0[q*8+1]); v.y = pk2(h0[q*8+2], h0[q*8+3]);
        v.z = pk2(h0[q*8+4], h0[q*8+5]); v.w = pk2(h0[q*8+6], h0[q*8+7]);
        ((uint4*)o0)[q] = v;
        uint4 w;
        w.x = pk2(h1[q*8+0], h1[q*8+1]); w.y = pk2(h1[q*8+2], h1[q*8+3]);
        w.z = pk2(h1[q*8+4], h1[q*8+5]); w.w = pk2(h1[q*8+6], h1[q*8+7]);
        ((uint4*)o1)[q] = w;
      }
    } else {
      float4* f0 = (float4*)(hfin + (size_t)n*2048 + (size_t)d0*16);
      float4* f1 = (float4*)(hfin + (size_t)n*2048 + (size_t)d1*16);
      #pragma unroll
      for (int q = 0; q < 4; q++){
        float4 v; v.x=h0[q*4+0]; v.y=h0[q*4+1]; v.z=h0[q*4+2]; v.w=h0[q*4+3];
        f0[q] = v;
        float4 w; w.x=h1[q*4+0]; w.y=h1[q*4+1]; w.z=h1[q*4+2]; w.w=h1[q*4+3];
        f1[q] = w;
      }
    }
    yz0[p] = (y0 + dp0 * xc0[p]) * zs[(size_t)n*128 + lane];
    yz1[p] = (y1 + dp1 * xc1[p]) * zs[(size_t)n*128 + 64 + lane];
  }

  // out_proj: oa[p] for output channel o=lane; 16 coalesced loads
  float oa[2] = {0.f, 0.f};
  #pragma unroll
  for (int q = 0; q < 16; q++){
    uint4 w4 = opI[q*64 + lane];
    float wf[8]; up8(w4, wf);
    #pragma unroll
    for (int j = 0; j < 8; j++){
      int d = q*8 + j;
      float b0, b1;
      if (d < 64){ b0 = rdl(yz0[0], d);      b1 = rdl(yz0[1], d); }
      else       { b0 = rdl(yz1[0], d - 64); b1 = rdl(yz1[1], d - 64); }
      oa[0] = fmaf(wf[j], b0, oa[0]);
      oa[1] = fmaf(wf[j], b1, oa[1]);
    }
  }

  const float nw = normw[lane];
  if (fusePre){
    float v[2];
    #pragma unroll
    for (int p = 0; p < 2; p++){
      int n = n0 + p;
      float x = oa[p] + xn[(size_t)n*64 + lane] + base_next[(size_t)n*64 + lane];
      float ss = x * x;
      for (int m = 32; m > 0; m >>= 1) ss += __shfl_xor(ss, m);
      x = x * rsqrtf(ss * (1.f/64.f) + 1e-5f) * nw;
      v[p] = x;
      xn[(size_t)n*64 + lane] = x;
    }
    float ac[4][2] = {};
    #pragma unroll
    for (int q = 0; q < 8; q++){
      uint4 w4[4];
      #pragma unroll
      for (int jj = 0; jj < 4; jj++) w4[jj] = ipI[(jj*8+q)*64 + lane];
      float wf[4][8];
      #pragma unroll
      for (int jj = 0; jj < 4; jj++) up8(w4[jj], wf[jj]);
      #pragma unroll
      for (int j = 0; j < 8; j++){
        int c = q*8 + j;
        float b0 = rdl(v[0], c), b1 = rdl(v[1], c);
        #pragma unroll
        for (int jj = 0; jj < 4; jj++){
          ac[jj][0] = fmaf(wf[jj][j], b0, ac[jj][0]);
          ac[jj][1] = fmaf(wf[jj][j], b1, ac[jj][1]);
        }
      }
    }
    #pragma unroll
    for (int p = 0; p < 2; p++){
      int n = n0 + p;
      xcpB[(size_t)n*128 + lane]      = ac[0][p];
      xcpB[(size_t)n*128 + 64 + lane] = ac[1][p];
      zs[(size_t)n*128 + lane]        = silu_f(ac[2][p]);
      zs[(size_t)n*128 + 64 + lane]   = silu_f(ac[3][p]);
    }
  } else {
    #pragma unroll
    for (int p = 0; p < 2; p++){
      int n = n0 + p;
      xcpB[(size_t)n*64 + lane] = oa[p] + xn[(size_t)n*64 + lane];
    }
  }
}

// ---- final conv1x1, transpose [N,64] -> [B,64,L] -----------------------
__global__ __launch_bounds__(256) void k_conv3(
    const float* __restrict__ out6, const float* __restrict__ w3T,
    const float* __restrict__ b3, float* __restrict__ out)
{
  __shared__ __align__(16) float t[64][65];
  const int tid = threadIdx.x;
  const int n0 = blockIdx.x * 64;
  #pragma unroll
  for (int i = 0; i < 16; i++){
    int idx = tid + 256*i;
    int r = idx >> 6, c = idx & 63;
    t[r][c] = out6[(size_t)(n0 + r)*64 + c];
  }
  __syncthreads();
  const int i = tid & 63;
  const int cb = (tid >> 6) * 16;
  float acc[16];
  #pragma unroll
  for (int j = 0; j < 16; j++) acc[j] = b3[cb + j];
  for (int o = 0; o < 64; o++){
    float xv = t[i][o];
    #pragma unroll
    for (int j = 0; j < 16; j++) acc[j] += w3T[o*64 + cb + j] * xv;
  }
  const int b = n0 >> 12;
  const int l = (n0 & 4095) + i;
  #pragma unroll
  for (int j = 0; j < 16; j++)
    out[(size_t)b*262144 + (size_t)(cb + j)*4096 + l] = acc[j];
}

extern "C" void kernel_launch(void* const* d_in, const int* in_sizes, int n_in,
                              void* d_out, int out_size, void* d_ws, size_t ws_size,
                              hipStream_t stream)
{
  const float* rgb  = (const float*)d_in[0];
  const float* dte  = (const float*)d_in[1];
  const float* w1   = (const float*)d_in[2];
  const float* b1   = (const float*)d_in[3];
  const float* w2   = (const float*)d_in[4];
  const float* b2   = (const float*)d_in[5];
  const float* w3   = (const float*)d_in[6];
  const float* b3   = (const float*)d_in[7];
  const float* nrm  = (const float*)d_in[8];
  const float* ipw  = (const float*)d_in[9];
  const float* c1w  = (const float*)d_in[10];
  const float* c1b  = (const float*)d_in[11];
  const float* xpw  = (const float*)d_in[12];
  const float* dtw  = (const float*)d_in[13];
  const float* dtb  = (const float*)d_in[14];
  const float* alog = (const float*)d_in[15];
  const float* Dpw  = (const float*)d_in[16];
  const float* opw  = (const float*)d_in[17];

  float* outc = (float*)d_out;
  float* hfin = outc + 524288;          // final fp32 h lives in d_out

  float* ws   = (float*)d_ws;
  float* xcp0 = ws;                     // [N,128] ping
  float* xcp1 = ws + 1048576;           // [N,128] pong
  float* rgbp = ws + 2097152;           // [N,64]
  float* dtep = ws + 2621440;           // [N,64]
  float* xnb  = ws + 3145728;           // [N,64]
  float* zsb  = ws + 3670016;           // [N,128]
  uint4* xpI  = (uint4*)(ws + 4718592); // 1024 uint4
  uint4* opI  = (uint4*)(ws + 4722688); // 1024
  uint4* dtI  = (uint4*)(ws + 4726784); // 512
  uint4* ipI  = (uint4*)(ws + 4728832); // 2048
  float* Aneg = ws + 4737024;           // [128][16]
  float* w1T  = ws + 4739072;           // [64][64]
  float* w2T  = ws + 4743168;
  float* w3T  = ws + 4747264;
  u16*   hbf  = (u16*)(ws + 4751360);   // [N,128,16] bf16 intermediate h

  k_prep<<<16, 256, 0, stream>>>(ipw, xpw, dtw, opw, w1, w2, w3, alog,
                                 xpI, opI, dtI, ipI, Aneg, w1T, w2T, w3T);
  k_convin<<<256, 256, 0, stream>>>(rgb, dte, w1T, b1, w2T, b2, rgbp, dtep);
  k_pre<<<1024, 256, 0, stream>>>(rgbp, nrm, ipI, xnb, xcp0, zsb);

  float* xa[2] = {xcp0, xcp1};
  for (int k = 0; k < 6; k++){
    const float* base = (k & 1) ? rgbp : dtep;   // unused when k==5
    k_step<<<1024, 256, 0, stream>>>(xa[k & 1], xa[(k & 1) ^ 1], zsb, xnb,
                                     hbf, hfin, base,
                                     xpI, opI, dtI, ipI, Aneg,
                                     c1w, c1b, dtb, Dpw, nrm,
                                     (k > 0) ? 1 : 0, (k < 5) ? 1 : 0);
  }
  k_conv3<<<128, 256, 0, stream>>>(xcp0, w3T, b3, outc);
}